// Round 8
// baseline (42.807 us; speedup 1.0000x reference)
//
#include <hip/hip_runtime.h>
#include <math.h>

// ChamferLoss: target [B,M,2] f32, actual [B,N,2] f32
// out = concat(forward[B,M], backward[B,N]) f32
//
// Round 8: packed-fp32 brute force, taxes removed.
//  - MFMA abandoned: rounds 6/7 bit-identical absmax proved the f16 MFMA
//    accumulator carries ~1e-3 error on cancellation-heavy d^2 (ulp-f16 of
//    the O(10) cross products) -> structurally over threshold at small d.
//  - SoA pre-pass (X[]/Y[] in ws) so v_pk_fma operands are adjacent VGPRs
//    (no deinterleave movs -- round 4's hidden tax).
//  - Resident packed coeffs cx/cy per query (round 4 rebuilt them).
//  - Inner: per 8 refs per query = 8 v_pk_fma_f32 + 4 v_min3_f32
//    = 1.72 inst/pair incl. prep (was ~2.78).
// Partial minima over RC=32 ref chunks, atomicMin on uint-encoded d^2.

typedef float f32x2 __attribute__((ext_vector_type(2)));

#define BLK 256
#define TM  8     // queries per thread
#define RC  32    // reference chunks per (b,dir)

__device__ __forceinline__ float min3f(float a, float b, float c) {
    float d;
    asm("v_min3_f32 %0, %1, %2, %3" : "=v"(d) : "v"(a), "v"(b), "v"(c));
    return d;
}

__global__ __launch_bounds__(256) void chamfer_init(unsigned int* __restrict__ out, int n) {
    int i = blockIdx.x * 256 + threadIdx.x;
    if (i < n) out[i] = 0x7F800000u;  // +inf
}

// SoA-ize both clouds into ws: per (set,b): X[S] then Y[S]   (set0=target)
__global__ __launch_bounds__(256) void chamfer_soa(
    const float2* __restrict__ tpts, const float2* __restrict__ apts,
    float* __restrict__ ws, int M, int N, int B, int S)
{
    int idx = blockIdx.x * 256 + threadIdx.x;
    int total = B * (M + N);
    if (idx >= total) return;
    int set, b, n;
    float2 p;
    if (idx < B * M) { set = 0; b = idx / M; n = idx % M; p = tpts[idx]; }
    else { int j = idx - B * M; set = 1; b = j / N; n = j % N; p = apts[j]; }
    float* base = ws + ((size_t)set * B + b) * (2 * (size_t)S);
    base[n] = p.x;
    base[S + n] = p.y;
}

__global__ __launch_bounds__(BLK, 4) void chamfer_partial(
    const float2* __restrict__ tpts,   // queries read AoS per-lane (coalesced)
    const float2* __restrict__ apts,
    const float* __restrict__ soa,     // refs read SoA wave-uniform
    unsigned int* __restrict__ out,    // [B*M + B*N], d^2 as uint bits
    int M, int N, int B, int S)
{
    const int b   = blockIdx.y;
    const int zc  = blockIdx.z;
    const int dir = zc & 1;       // 0: forward (queries=target), 1: backward
    const int rc  = zc >> 1;      // which reference chunk

    const float2* __restrict__ Q = dir ? apts : tpts;
    const int NQ = dir ? N : M;
    const int NR = dir ? M : N;
    const int rsel = 1 - dir;     // refs: dir0 -> actual(set1), dir1 -> target(set0)
    unsigned int* __restrict__ o =
        out + (dir ? ((size_t)B * M + (size_t)b * N) : ((size_t)b * M));

    const float2* __restrict__ q = Q + (size_t)b * NQ;
    const float*  __restrict__ RX = soa + ((size_t)rsel * B + b) * (2 * (size_t)S);
    const float*  __restrict__ RY = RX + S;

    const int clen = (NR + RC - 1) / RC;
    const int rbeg = rc * clen;
    const int rend = (rbeg + clen < NR) ? (rbeg + clen) : NR;
    if (rbeg >= rend) return;

    int   qi[TM];
    float qn[TM], mn[TM];
    f32x2 cx[TM], cy[TM];         // resident packed coeffs (-2qx, -2qy)
#pragma unroll
    for (int k = 0; k < TM; ++k) {
        qi[k] = blockIdx.x * (BLK * TM) + k * BLK + (int)threadIdx.x;
        int idx = qi[k] < NQ ? qi[k] : NQ - 1;
        float2 p = q[idx];
        cx[k] = (f32x2)(-2.0f * p.x);
        cy[k] = (f32x2)(-2.0f * p.y);
        qn[k] = fmaf(p.y, p.y, p.x * p.x);
        mn[k] = 3.0e38f;
    }

    int n = rbeg;
    // main: 8 refs per iteration, SoA float4 loads -> adjacent-reg pairs
    for (; n + 8 <= rend; n += 8) {
        float4 xa = *(const float4*)&RX[n];     // x0..x3 (wave-uniform)
        float4 xb = *(const float4*)&RX[n + 4]; // x4..x7
        float4 ya = *(const float4*)&RY[n];
        float4 yb = *(const float4*)&RY[n + 4];
        f32x2 px0 = (f32x2){xa.x, xa.y}, px1 = (f32x2){xa.z, xa.w};
        f32x2 px2 = (f32x2){xb.x, xb.y}, px3 = (f32x2){xb.z, xb.w};
        f32x2 py0 = (f32x2){ya.x, ya.y}, py1 = (f32x2){ya.z, ya.w};
        f32x2 py2 = (f32x2){yb.x, yb.y}, py3 = (f32x2){yb.z, yb.w};
        f32x2 va0 = __builtin_elementwise_fma(py0, py0, px0 * px0);
        f32x2 va1 = __builtin_elementwise_fma(py1, py1, px1 * px1);
        f32x2 va2 = __builtin_elementwise_fma(py2, py2, px2 * px2);
        f32x2 va3 = __builtin_elementwise_fma(py3, py3, px3 * px3);
#pragma unroll
        for (int k = 0; k < TM; ++k) {
            f32x2 v0 = __builtin_elementwise_fma(cx[k], px0,
                        __builtin_elementwise_fma(cy[k], py0, va0));
            f32x2 v1 = __builtin_elementwise_fma(cx[k], px1,
                        __builtin_elementwise_fma(cy[k], py1, va1));
            f32x2 v2 = __builtin_elementwise_fma(cx[k], px2,
                        __builtin_elementwise_fma(cy[k], py2, va2));
            f32x2 v3 = __builtin_elementwise_fma(cx[k], px3,
                        __builtin_elementwise_fma(cy[k], py3, va3));
            float m = min3f(v0.x, v0.y, v1.x);
            m       = min3f(m, v1.y, v2.x);
            m       = min3f(m, v2.y, v3.x);
            mn[k]   = min3f(m, v3.y, mn[k]);
        }
    }
    // tail
    for (; n < rend; ++n) {
        float x = RX[n], y = RY[n];
        float va = fmaf(y, y, x * x);
#pragma unroll
        for (int k = 0; k < TM; ++k) {
            float v = fmaf(cx[k].x, x, fmaf(cy[k].x, y, va));
            mn[k] = fminf(mn[k], v);
        }
    }

#pragma unroll
    for (int k = 0; k < TM; ++k) {
        if (qi[k] < NQ) {
            float d2 = fmaxf(mn[k] + qn[k], 0.0f);
            atomicMin(&o[qi[k]], __float_as_uint(d2));
        }
    }
}

__global__ __launch_bounds__(256) void chamfer_sqrt(unsigned int* __restrict__ io, int n) {
    int i = blockIdx.x * 256 + threadIdx.x;
    if (i < n) ((float*)io)[i] = sqrtf(__uint_as_float(io[i]));
}

// ---------- fallback (round-5 proven path) if ws too small ----------
__global__ __launch_bounds__(BLK) void chamfer_partial_aos(
    const float2* __restrict__ tpts, const float2* __restrict__ apts,
    unsigned int* __restrict__ out, int M, int N, int B)
{
    const int b = blockIdx.y, zc = blockIdx.z;
    const int dir = zc & 1, rc = zc >> 1;
    const float2* __restrict__ Q = dir ? apts : tpts;
    const float2* __restrict__ R = dir ? tpts : apts;
    const int NQ = dir ? N : M, NR = dir ? M : N;
    unsigned int* __restrict__ o =
        out + (dir ? ((size_t)B * M + (size_t)b * N) : ((size_t)b * M));
    const float2* __restrict__ q = Q + (size_t)b * NQ;
    const float2* __restrict__ r = R + (size_t)b * NR;
    const int clen = (NR + RC - 1) / RC;
    const int rbeg = rc * clen;
    const int rend = (rbeg + clen < NR) ? (rbeg + clen) : NR;
    if (rbeg >= rend) return;
    int qi[TM]; float n2x[TM], n2y[TM], qn[TM], mn[TM];
#pragma unroll
    for (int k = 0; k < TM; ++k) {
        qi[k] = blockIdx.x * (BLK * TM) + k * BLK + (int)threadIdx.x;
        int idx = qi[k] < NQ ? qi[k] : NQ - 1;
        float2 p = q[idx];
        n2x[k] = -2.0f * p.x; n2y[k] = -2.0f * p.y;
        qn[k] = fmaf(p.y, p.y, p.x * p.x); mn[k] = 3.0e38f;
    }
    for (int n = rbeg; n < rend; ++n) {
        float2 p = r[n];
        float va = fmaf(p.y, p.y, p.x * p.x);
#pragma unroll
        for (int k = 0; k < TM; ++k)
            mn[k] = fminf(mn[k], fmaf(n2x[k], p.x, fmaf(n2y[k], p.y, va)));
    }
#pragma unroll
    for (int k = 0; k < TM; ++k)
        if (qi[k] < NQ)
            atomicMin(&o[qi[k]], __float_as_uint(fmaxf(mn[k] + qn[k], 0.0f)));
}

extern "C" void kernel_launch(void* const* d_in, const int* in_sizes, int n_in,
                              void* d_out, int out_size, void* d_ws, size_t ws_size,
                              hipStream_t stream) {
    const float2* tpts = (const float2*)d_in[0];
    const float2* apts = (const float2*)d_in[1];
    unsigned int* out = (unsigned int*)d_out;

    const int B = 16;
    const int M = in_sizes[0] / (B * 2);
    const int N = in_sizes[1] / (B * 2);
    const int S = M > N ? M : N;
    const int total = B * (M + N);

    chamfer_init<<<(total + 255) / 256, 256, 0, stream>>>(out, total);

    size_t soa_bytes = (size_t)2 * B * 2 * S * sizeof(float);
    dim3 grid((S + BLK * TM - 1) / (BLK * TM), B, 2 * RC);

    if (ws_size >= soa_bytes) {
        float* soa = (float*)d_ws;
        chamfer_soa<<<(total + 255) / 256, 256, 0, stream>>>(
            tpts, apts, soa, M, N, B, S);
        chamfer_partial<<<grid, dim3(BLK), 0, stream>>>(
            tpts, apts, soa, out, M, N, B, S);
    } else {
        chamfer_partial_aos<<<grid, dim3(BLK), 0, stream>>>(
            tpts, apts, out, M, N, B);
    }

    chamfer_sqrt<<<(total + 255) / 256, 256, 0, stream>>>(out, total);
}